// Round 15
// baseline (130.831 us; speedup 1.0000x reference)
//
#include <hip/hip_runtime.h>

#define NN 10000
#define NE 640000
#define IN_DIM 128
#define HID_DIM 512
#define OUT_DIM 512
#define NB 10240          // padded bin count (>= NN, mult of 1024)
#define P_PART 128
#define EPB (NE / P_PART) // 5000 edges per partition

typedef __attribute__((ext_vector_type(8))) short short8;
typedef __attribute__((ext_vector_type(4))) float f32x4;
typedef __attribute__((ext_vector_type(2))) float f32x2;

__device__ __forceinline__ ushort f2b(float f) {
    union { float f; uint i; } c; c.f = f;
    uint x = c.i;
    uint r = (x + 0x7fffu + ((x >> 16) & 1u)) >> 16;
    return (ushort)r;
}
__device__ __forceinline__ float blo(uint a) {
    union { uint i; float f; } c; c.i = a << 16; return c.f;
}
__device__ __forceinline__ float bhi(uint a) {
    union { uint i; float f; } c; c.i = a & 0xffff0000u; return c.f;
}

// Async global->LDS, 16B per lane, linear LDS dest (wave-uniform base + lane*16).
__device__ __forceinline__ void gl_lds16(const ushort* g, ushort* l) {
    __builtin_amdgcn_global_load_lds((const __attribute__((address_space(1))) uint*)g,
                                     (__attribute__((address_space(3))) uint*)l, 16, 0, 0);
}

// Fused: blocks [0,128) packed dual histogram (dst low16 | src high16),
// [128,192) W1^T, [192,448) W2^T.
__global__ __launch_bounds__(1024) void histw_kernel(const int* __restrict__ ei,
                                                     uint* __restrict__ pcnt,
                                                     const float* __restrict__ W1,
                                                     ushort* __restrict__ W1t,
                                                     const float* __restrict__ W2,
                                                     ushort* __restrict__ W2t) {
    __shared__ int h[NB];
    int b = blockIdx.x;
    int t = threadIdx.x;
    if (b < 128) {
        int p = b;
        const int* __restrict__ srcp = ei;
        const int* __restrict__ dstp = ei + NE;
        for (int i = t; i < NB; i += 1024) h[i] = 0;
        __syncthreads();
        int base = p * EPB;
        for (int i = t; i < EPB; i += 1024) {
            atomicAdd(&h[dstp[base + i]], 1);        // dst count in low16
            atomicAdd(&h[srcp[base + i]], 1 << 16);  // src count in high16
        }
        __syncthreads();
        for (int i = t; i < NB; i += 1024) pcnt[(size_t)p * NB + i] = (uint)h[i];
        return;
    }
    // 32x32 transpose tiles, 1024 threads = one element each
    float* tld = (float*)h;  // [32][33]
    const float* W; ushort* Wt; int K, N, k0, n0;
    if (b < 192) {
        int bb = b - 128;
        W = W1; Wt = W1t; K = IN_DIM; N = HID_DIM;
        k0 = (bb & 3) * 32; n0 = (bb >> 2) * 32;
    } else {
        int bb = b - 192;
        W = W2; Wt = W2t; K = HID_DIM; N = OUT_DIM;
        k0 = (bb & 15) * 32; n0 = (bb >> 4) * 32;
    }
    int r = t >> 5, c = t & 31;
    tld[r * 33 + c] = W[(size_t)(k0 + r) * N + n0 + c];
    __syncthreads();
    Wt[(size_t)(n0 + r) * K + k0 + c] = f2b(tld[c * 33 + r]);
}

// Column reduce over partitions (packed pcnt): deg_in, exclusive poff (ushort),
// norms. Only 160 waves exist -> latency-bound; batch 16 loads per step for MLP.
__global__ __launch_bounds__(256) void colreduce_kernel(const uint* __restrict__ pcnt,
                                                        ushort* __restrict__ poff,
                                                        int* __restrict__ deg_in,
                                                        float* __restrict__ norm_src,
                                                        float* __restrict__ norm_dst) {
    int v = blockIdx.x * 256 + threadIdx.x;  // 0..NB-1
    int s = 0, s2 = 0;
    for (int p0 = 0; p0 < P_PART; p0 += 16) {
        uint c[16];
#pragma unroll
        for (int q = 0; q < 16; q++) c[q] = pcnt[(size_t)(p0 + q) * NB + v];
#pragma unroll
        for (int q = 0; q < 16; q++) {
            poff[(size_t)(p0 + q) * NB + v] = (ushort)s;
            s += (int)(c[q] & 0xffffu);
            s2 += (int)(c[q] >> 16);
        }
    }
    deg_in[v] = s;
    if (v < NN) {
        norm_dst[v] = rsqrtf(fmaxf((float)s, 1.0f));
        norm_src[v] = rsqrtf(fmaxf((float)s2, 1.0f));
    }
}

// Fused: blocks [0,128) = CSR fill (redundant per-block scan of deg_in via shfl;
// block 0 publishes row_off); blocks [128,441) = featconv (bf16(feat * norm_src)).
__global__ __launch_bounds__(1024) void fillfeat_kernel(const int* __restrict__ src,
                                                        const int* __restrict__ dst,
                                                        const int* __restrict__ deg_in,
                                                        const ushort* __restrict__ poff,
                                                        int* __restrict__ row_off,
                                                        int* __restrict__ csr_src,
                                                        const float* __restrict__ feat,
                                                        const float* __restrict__ norm_src,
                                                        ushort* __restrict__ featb) {
    int b = blockIdx.x;
    int t = threadIdx.x;
    if (b >= 128) {  // featconv: featb = bf16(feat * norm_src), pre-scaled
        int i = (b - 128) * 1024 + t;  // float4 index
        if (i < NN * IN_DIM / 4) {
            float4 v = ((const float4*)feat)[i];
            float s = norm_src[i >> 5];
            ushort4 o;
            o.x = f2b(v.x * s); o.y = f2b(v.y * s); o.z = f2b(v.z * s); o.w = f2b(v.w * s);
            ((ushort4*)featb)[i] = o;
        }
        return;
    }
    __shared__ int cur[NB];
    __shared__ int wsum[16];
    int p = b;
    // redundant per-block exclusive scan of deg_in[0..NB): segment sums + shfl scan
    const int PER = NB / 1024;  // 10
    int base = t * PER;
    int local[PER];
    int s = 0;
#pragma unroll
    for (int i = 0; i < PER; i++) {
        int v = deg_in[base + i];
        local[i] = s;
        s += v;
    }
    int lane = t & 63, wv = t >> 6;  // 16 waves
    // inclusive scan of segment sums within the wave
    int sc = s;
#pragma unroll
    for (int d = 1; d < 64; d <<= 1) {
        int x = __shfl_up(sc, d);
        if (lane >= d) sc += x;
    }
    if (lane == 63) wsum[wv] = sc;
    __syncthreads();
    if (t < 16) {
        int w = wsum[t];
#pragma unroll
        for (int d = 1; d < 16; d <<= 1) {
            int x = __shfl_up(w, d);
            if (t >= d) w += x;
        }
        wsum[t] = w;  // inclusive wave-prefix
    }
    __syncthreads();
    int excl = sc - s + (wv ? wsum[wv - 1] : 0);  // exclusive prefix of this segment
#pragma unroll
    for (int i = 0; i < PER; i++) {
        int idx = base + i;
        int ro = excl + local[i];
        cur[idx] = ro + (int)poff[(size_t)p * NB + idx];
        if (p == 0 && idx <= NN) row_off[idx] = ro;
    }
    __syncthreads();
    int ebase = p * EPB;
    for (int i = t; i < EPB; i += 1024) {
        int d = dst[ebase + i];
        int slot = atomicAdd(&cur[d], 1);
        csr_src[slot] = src[ebase + i];
    }
}

// 4 waves per block, one node per wave; 128 bf16 dims = 64 uints of the row.
// Wave-uniform row base via readfirstlane -> saddr-form dword gathers.
// Unroll 16 main loop for deeper MLP. Per-wave work identical to 1-wave-block
// version (bitwise-stable); packing improves per-CU occupancy and dispatch.
__global__ __launch_bounds__(256) void agg1_kernel(const uint* __restrict__ fb,
                                                   const int* __restrict__ row_off,
                                                   const int* __restrict__ csr_src,
                                                   const float* __restrict__ norm_dst,
                                                   uint* __restrict__ aggb) {
    int node = blockIdx.x * 4 + (threadIdx.x >> 6);
    uint lane = threadIdx.x & 63u;
    int beg = row_off[node], end = row_off[node + 1];
    f32x2 acc = {0.f, 0.f};
    int i = beg;
    for (; i + 16 <= end; i += 16) {
        const uint* rp[16];
#pragma unroll
        for (int j = 0; j < 16; j++)
            rp[j] = fb + (uint)__builtin_amdgcn_readfirstlane(csr_src[i + j]) * 64u;
        uint a[16];
#pragma unroll
        for (int j = 0; j < 16; j++) a[j] = rp[j][lane];
#pragma unroll
        for (int j = 0; j < 16; j++) {
            f32x2 v; v.x = blo(a[j]); v.y = bhi(a[j]);
            acc += v;
        }
    }
    for (; i + 8 <= end; i += 8) {
        const uint* rp[8];
#pragma unroll
        for (int j = 0; j < 8; j++)
            rp[j] = fb + (uint)__builtin_amdgcn_readfirstlane(csr_src[i + j]) * 64u;
        uint a[8];
#pragma unroll
        for (int j = 0; j < 8; j++) a[j] = rp[j][lane];
#pragma unroll
        for (int j = 0; j < 8; j++) {
            f32x2 v; v.x = blo(a[j]); v.y = bhi(a[j]);
            acc += v;
        }
    }
    for (; i < end; i++) {
        const uint* rp = fb + (uint)__builtin_amdgcn_readfirstlane(csr_src[i]) * 64u;
        uint a = rp[lane];
        f32x2 v; v.x = blo(a); v.y = bhi(a);
        acc += v;
    }
    float nd = norm_dst[node];
    aggb[node * 64 + lane] = (uint)f2b(acc.x * nd) | ((uint)f2b(acc.y * nd) << 16);
}

// Sliced 512-dim gather, 4 waves per block, XCD-aware (node, slice) mapping.
// b in [0,10000): xcd = b&7, slice = xcd&3, node = (b>>3)*8 + (xcd>>2)*4 + wid.
// Coverage: (b>>3) in [0,1250) x {0,1} x wid in [0,4) spans all 10000 nodes;
// each (node, slice) exactly once; XCD x touches ONLY slice x&3 -> its 2.56 MB
// hb slice stays per-XCD-L2 resident (same property as the 1-wave version).
__global__ __launch_bounds__(256) void agg2_kernel(const uint* __restrict__ hb,
                                                   const int* __restrict__ row_off,
                                                   const int* __restrict__ csr_src,
                                                   const float* __restrict__ norm_dst,
                                                   uint* __restrict__ aggb) {
    uint b = blockIdx.x;
    uint xcd = b & 7u;
    uint wid = threadIdx.x >> 6;
    int node = (int)((b >> 3) * 8u + (xcd >> 2) * 4u + wid);
    uint t = (xcd & 3u) * 64u + (threadIdx.x & 63u);  // uint index 0..255
    int beg = row_off[node], end = row_off[node + 1];
    f32x2 acc = {0.f, 0.f};
    int i = beg;
    for (; i + 16 <= end; i += 16) {
        const uint* rp[16];
#pragma unroll
        for (int j = 0; j < 16; j++)
            rp[j] = hb + (uint)__builtin_amdgcn_readfirstlane(csr_src[i + j]) * 256u;
        uint a[16];
#pragma unroll
        for (int j = 0; j < 16; j++) a[j] = rp[j][t];
#pragma unroll
        for (int j = 0; j < 16; j++) {
            f32x2 v; v.x = blo(a[j]); v.y = bhi(a[j]);
            acc += v;
        }
    }
    for (; i + 8 <= end; i += 8) {
        const uint* rp[8];
#pragma unroll
        for (int j = 0; j < 8; j++)
            rp[j] = hb + (uint)__builtin_amdgcn_readfirstlane(csr_src[i + j]) * 256u;
        uint a[8];
#pragma unroll
        for (int j = 0; j < 8; j++) a[j] = rp[j][t];
#pragma unroll
        for (int j = 0; j < 8; j++) {
            f32x2 v; v.x = blo(a[j]); v.y = bhi(a[j]);
            acc += v;
        }
    }
    for (; i < end; i++) {
        const uint* rp = hb + (uint)__builtin_amdgcn_readfirstlane(csr_src[i]) * 256u;
        uint a = rp[t];
        f32x2 v; v.x = blo(a); v.y = bhi(a);
        acc += v;
    }
    float nd = norm_dst[node];
    aggb[(uint)node * 256u + t] = (uint)f2b(acc.x * nd) | ((uint)f2b(acc.y * nd) << 16);
}

// bf16 MFMA GEMM: C[M][N] = A[M][K] @ Bt[N][K]^T (+bias).
// BM=128, BN=64, BK=32, 256 threads = 4 waves (2x2 of 64x32), double-buffered
// LDS, 2-phase schedule: stage(next) -> ds_read/MFMA(cur) -> one barrier/K-step.
// BN=64 doubles the grid (632 blocks) -> tail 1.5 vs 2.0 tile-units on 256 CUs.
// Fragment-ordered LDS via global_load_lds with pre-swizzled per-lane source.
// A must be padded to BM-multiple rows (OOB rows read garbage, masked at C-write).
// EPI 0: fp32 out = acc + bias.   EPI 1: bf16 out = relu(acc+bias) * scale[row].
template <int EPI>
__global__ __launch_bounds__(256) void gemm_bf16_kernel(const ushort* __restrict__ A,
                                                        const ushort* __restrict__ Bt,
                                                        const float* __restrict__ bias,
                                                        const float* __restrict__ scale,
                                                        void* __restrict__ Cout,
                                                        int M, int K, int N) {
    __shared__ __align__(16) ushort As[2][128 * 32];  // 8 KB each, fragment order
    __shared__ __align__(16) ushort Bs[2][64 * 32];   // 4 KB each
    int tid = threadIdx.x;
    int lane = tid & 63;
    int wid = tid >> 6;
    int bm = blockIdx.x * 128;
    int bn = blockIdx.y * 64;
    int wm = (wid & 1) * 64;
    int wn = (wid >> 1) * 32;

    // Pre-swizzled source coords: LDS chunk c holds (row, kq):
    // row = ((c>>6)<<4)|(c&15), kq = (c>>4)&3.
    int c0 = tid, c1 = 256 + tid;
    int row0 = ((c0 >> 6) << 4) | (c0 & 15), kq0 = (c0 >> 4) & 3;
    int row1 = ((c1 >> 6) << 4) | (c1 & 15), kq1 = (c1 >> 4) & 3;
    const ushort* sA0 = A + (size_t)(bm + row0) * K + kq0 * 8;
    const ushort* sA1 = A + (size_t)(bm + row1) * K + kq1 * 8;
    const ushort* sB0 = Bt + (size_t)(bn + row0) * K + kq0 * 8;  // rows 0..63
    uint lo0 = (uint)(wid * 64) * 8u;          // ushort index of this wave's chunk group 0
    uint lo1 = (uint)(256 + wid * 64) * 8u;    // group 1 (A only)

    f32x4 acc[4][2] = {};

    const int NT = K / 32;
    // prologue: stage tile 0 into buffer 0
    gl_lds16(sA0, &As[0][lo0]);
    gl_lds16(sA1, &As[0][lo1]);
    gl_lds16(sB0, &Bs[0][lo0]);
    __syncthreads();

    int cur = 0;
    for (int t = 0; t < NT; t++) {
        if (t + 1 < NT) {  // stage next tile into the other buffer
            int kn = (t + 1) * 32;
            gl_lds16(sA0 + kn, &As[cur ^ 1][lo0]);
            gl_lds16(sA1 + kn, &As[cur ^ 1][lo1]);
            gl_lds16(sB0 + kn, &Bs[cur ^ 1][lo0]);
        }
        short8 af[4], bfr[2];
        int fo = ((lane >> 4) << 4) + (lane & 15);
#pragma unroll
        for (int i = 0; i < 4; i++) {
            int j = (((wm >> 4) + i) << 6) + fo;
            af[i] = *(const short8*)(&As[cur][j * 8]);
        }
#pragma unroll
        for (int i = 0; i < 2; i++) {
            int j = (((wn >> 4) + i) << 6) + fo;
            bfr[i] = *(const short8*)(&Bs[cur][j * 8]);
        }
#pragma unroll
        for (int i = 0; i < 4; i++)
#pragma unroll
            for (int jn = 0; jn < 2; jn++)
                acc[i][jn] = __builtin_amdgcn_mfma_f32_16x16x32_bf16(af[i], bfr[jn], acc[i][jn], 0, 0, 0);
        if (t + 1 < NT) {
            __syncthreads();  // drains next-tile vmcnt + guards buffer swap
            cur ^= 1;
        }
    }

#pragma unroll
    for (int i = 0; i < 4; i++) {
#pragma unroll
        for (int jn = 0; jn < 2; jn++) {
            int col = bn + wn + jn * 16 + (lane & 15);
            float bv = bias[col];
#pragma unroll
            for (int r = 0; r < 4; r++) {
                int gm = bm + wm + i * 16 + ((lane >> 4) << 2) + r;
                if (gm < M) {
                    float v = acc[i][jn][r] + bv;
                    if (EPI == 1) {
                        v = fmaxf(v, 0.f) * scale[gm];
                        ((ushort*)Cout)[(size_t)gm * N + col] = f2b(v);
                    } else {
                        ((float*)Cout)[(size_t)gm * N + col] = v;
                    }
                }
            }
        }
    }
}

extern "C" void kernel_launch(void* const* d_in, const int* in_sizes, int n_in,
                              void* d_out, int out_size, void* d_ws, size_t ws_size,
                              hipStream_t stream) {
    const float* feat = (const float*)d_in[0];
    const int* ei = (const int*)d_in[1];
    const float* W1 = (const float*)d_in[2];
    const float* b1 = (const float*)d_in[3];
    const float* W2 = (const float*)d_in[4];
    const float* b2 = (const float*)d_in[5];
    float* out = (float*)d_out;

    const int* src = ei;
    const int* dst = ei + NE;
    const int NNP = 10112;  // NN padded to BM=128 multiple (A-panel OOB safety)

    char* ws = (char*)d_ws;
    size_t off = 0;
    auto alloc = [&](size_t bytes) -> void* {
        void* p = ws + off;
        off += (bytes + 255) & ~(size_t)255;
        return p;
    };
    // ---- fixed region ----
    int* row_off = (int*)alloc((NN + 16) * sizeof(int));
    int* deg_in = (int*)alloc(NB * sizeof(int));
    float* norm_src = (float*)alloc(NN * sizeof(float));
    float* norm_dst = (float*)alloc(NN * sizeof(float));
    int* csr_src = (int*)alloc(NE * sizeof(int));
    ushort* featb = (ushort*)alloc((size_t)NN * IN_DIM * 2);
    ushort* W1t = (ushort*)alloc((size_t)HID_DIM * IN_DIM * 2);
    ushort* W2t = (ushort*)alloc((size_t)OUT_DIM * HID_DIM * 2);
    // ---- union region: prep {pcnt, poff} overlaps main {agg1b, hb, agg2b}.
    // Safe: pcnt last read in colreduce, poff last read in fillfeat; agg1b first
    // written by agg1, hb by gemm1, agg2b by agg2 — all strictly later.
    size_t union_base = off;
    uint* pcnt = (uint*)alloc((size_t)P_PART * NB * sizeof(uint));        // 5.24 MB packed
    ushort* poff = (ushort*)alloc((size_t)P_PART * NB * sizeof(ushort));  // 2.62 MB
    off = union_base;
    ushort* agg1b = (ushort*)alloc((size_t)NNP * IN_DIM * 2);   // padded A-panel
    ushort* hb = (ushort*)alloc((size_t)NN * HID_DIM * 2);      // 10.24 MB
    ushort* agg2b = (ushort*)alloc((size_t)NNP * HID_DIM * 2);  // padded A-panel

    // ---- graph prep (no global atomics) + W transposes ----
    histw_kernel<<<448, 1024, 0, stream>>>(ei, pcnt, W1, W1t, W2, W2t);
    colreduce_kernel<<<NB / 256, 256, 0, stream>>>(pcnt, poff, deg_in, norm_src, norm_dst);
    fillfeat_kernel<<<128 + 313, 1024, 0, stream>>>(src, dst, deg_in, poff, row_off, csr_src,
                                                    feat, norm_src, featb);

    // ---- layer 1 (agg1: 4 nodes per 256-thr block) ----
    agg1_kernel<<<NN / 4, 256, 0, stream>>>((const uint*)featb, row_off, csr_src, norm_dst, (uint*)agg1b);
    {
        dim3 grid(NNP / 128, HID_DIM / 64);
        gemm_bf16_kernel<1><<<grid, 256, 0, stream>>>(agg1b, W1t, b1, norm_src, hb, NN, IN_DIM, HID_DIM);
    }
    // ---- layer 2 (agg2: 4 (node,slice) waves per block, XCD-sliced; 10000 blocks) ----
    agg2_kernel<<<NN, 256, 0, stream>>>((const uint*)hb, row_off, csr_src, norm_dst, (uint*)agg2b);
    {
        dim3 grid(NNP / 128, OUT_DIM / 64);
        gemm_bf16_kernel<0><<<grid, 256, 0, stream>>>(agg2b, W2t, b2, nullptr, out, NN, HID_DIM, OUT_DIM);
    }
}

// Round 16
// 110.575 us; speedup vs baseline: 1.1832x; 1.1832x over previous
//
#include <hip/hip_runtime.h>

#define NN 10000
#define NE 640000
#define IN_DIM 128
#define HID_DIM 512
#define OUT_DIM 512
#define NB 10240          // padded bin count (>= NN, mult of 1024)
#define P_PART 128
#define EPB (NE / P_PART) // 5000 edges per partition

typedef __attribute__((ext_vector_type(8))) short short8;
typedef __attribute__((ext_vector_type(4))) float f32x4;
typedef __attribute__((ext_vector_type(2))) float f32x2;

__device__ __forceinline__ ushort f2b(float f) {
    union { float f; uint i; } c; c.f = f;
    uint x = c.i;
    uint r = (x + 0x7fffu + ((x >> 16) & 1u)) >> 16;
    return (ushort)r;
}
__device__ __forceinline__ float blo(uint a) {
    union { uint i; float f; } c; c.i = a << 16; return c.f;
}
__device__ __forceinline__ float bhi(uint a) {
    union { uint i; float f; } c; c.i = a & 0xffff0000u; return c.f;
}

// Async global->LDS, 16B per lane, linear LDS dest (wave-uniform base + lane*16).
__device__ __forceinline__ void gl_lds16(const ushort* g, ushort* l) {
    __builtin_amdgcn_global_load_lds((const __attribute__((address_space(1))) uint*)g,
                                     (__attribute__((address_space(3))) uint*)l, 16, 0, 0);
}

// Fused: blocks [0,128) packed dual histogram (dst low16 | src high16),
// [128,192) W1^T, [192,448) W2^T.
__global__ __launch_bounds__(1024) void histw_kernel(const int* __restrict__ ei,
                                                     uint* __restrict__ pcnt,
                                                     const float* __restrict__ W1,
                                                     ushort* __restrict__ W1t,
                                                     const float* __restrict__ W2,
                                                     ushort* __restrict__ W2t) {
    __shared__ int h[NB];
    int b = blockIdx.x;
    int t = threadIdx.x;
    if (b < 128) {
        int p = b;
        const int* __restrict__ srcp = ei;
        const int* __restrict__ dstp = ei + NE;
        for (int i = t; i < NB; i += 1024) h[i] = 0;
        __syncthreads();
        int base = p * EPB;
        for (int i = t; i < EPB; i += 1024) {
            atomicAdd(&h[dstp[base + i]], 1);        // dst count in low16
            atomicAdd(&h[srcp[base + i]], 1 << 16);  // src count in high16
        }
        __syncthreads();
        for (int i = t; i < NB; i += 1024) pcnt[(size_t)p * NB + i] = (uint)h[i];
        return;
    }
    // 32x32 transpose tiles, 1024 threads = one element each
    float* tld = (float*)h;  // [32][33]
    const float* W; ushort* Wt; int K, N, k0, n0;
    if (b < 192) {
        int bb = b - 128;
        W = W1; Wt = W1t; K = IN_DIM; N = HID_DIM;
        k0 = (bb & 3) * 32; n0 = (bb >> 2) * 32;
    } else {
        int bb = b - 192;
        W = W2; Wt = W2t; K = HID_DIM; N = OUT_DIM;
        k0 = (bb & 15) * 32; n0 = (bb >> 4) * 32;
    }
    int r = t >> 5, c = t & 31;
    tld[r * 33 + c] = W[(size_t)(k0 + r) * N + n0 + c];
    __syncthreads();
    Wt[(size_t)(n0 + r) * K + k0 + c] = f2b(tld[c * 33 + r]);
}

// Column reduce over partitions (packed pcnt): deg_in, exclusive poff (ushort),
// norms. Only 160 waves exist -> latency-bound; batch 16 loads per step for MLP.
__global__ __launch_bounds__(256) void colreduce_kernel(const uint* __restrict__ pcnt,
                                                        ushort* __restrict__ poff,
                                                        int* __restrict__ deg_in,
                                                        float* __restrict__ norm_src,
                                                        float* __restrict__ norm_dst) {
    int v = blockIdx.x * 256 + threadIdx.x;  // 0..NB-1
    int s = 0, s2 = 0;
    for (int p0 = 0; p0 < P_PART; p0 += 16) {
        uint c[16];
#pragma unroll
        for (int q = 0; q < 16; q++) c[q] = pcnt[(size_t)(p0 + q) * NB + v];
#pragma unroll
        for (int q = 0; q < 16; q++) {
            poff[(size_t)(p0 + q) * NB + v] = (ushort)s;
            s += (int)(c[q] & 0xffffu);
            s2 += (int)(c[q] >> 16);
        }
    }
    deg_in[v] = s;
    if (v < NN) {
        norm_dst[v] = rsqrtf(fmaxf((float)s, 1.0f));
        norm_src[v] = rsqrtf(fmaxf((float)s2, 1.0f));
    }
}

// Fused: blocks [0,128) = CSR fill (redundant per-block scan of deg_in via shfl;
// block 0 publishes row_off); blocks [128,441) = featconv (bf16(feat * norm_src)).
__global__ __launch_bounds__(1024) void fillfeat_kernel(const int* __restrict__ src,
                                                        const int* __restrict__ dst,
                                                        const int* __restrict__ deg_in,
                                                        const ushort* __restrict__ poff,
                                                        int* __restrict__ row_off,
                                                        int* __restrict__ csr_src,
                                                        const float* __restrict__ feat,
                                                        const float* __restrict__ norm_src,
                                                        ushort* __restrict__ featb) {
    int b = blockIdx.x;
    int t = threadIdx.x;
    if (b >= 128) {  // featconv: featb = bf16(feat * norm_src), pre-scaled
        int i = (b - 128) * 1024 + t;  // float4 index
        if (i < NN * IN_DIM / 4) {
            float4 v = ((const float4*)feat)[i];
            float s = norm_src[i >> 5];
            ushort4 o;
            o.x = f2b(v.x * s); o.y = f2b(v.y * s); o.z = f2b(v.z * s); o.w = f2b(v.w * s);
            ((ushort4*)featb)[i] = o;
        }
        return;
    }
    __shared__ int cur[NB];
    __shared__ int wsum[16];
    int p = b;
    // redundant per-block exclusive scan of deg_in[0..NB): segment sums + shfl scan
    const int PER = NB / 1024;  // 10
    int base = t * PER;
    int local[PER];
    int s = 0;
#pragma unroll
    for (int i = 0; i < PER; i++) {
        int v = deg_in[base + i];
        local[i] = s;
        s += v;
    }
    int lane = t & 63, wv = t >> 6;  // 16 waves
    // inclusive scan of segment sums within the wave
    int sc = s;
#pragma unroll
    for (int d = 1; d < 64; d <<= 1) {
        int x = __shfl_up(sc, d);
        if (lane >= d) sc += x;
    }
    if (lane == 63) wsum[wv] = sc;
    __syncthreads();
    if (t < 16) {
        int w = wsum[t];
#pragma unroll
        for (int d = 1; d < 16; d <<= 1) {
            int x = __shfl_up(w, d);
            if (t >= d) w += x;
        }
        wsum[t] = w;  // inclusive wave-prefix
    }
    __syncthreads();
    int excl = sc - s + (wv ? wsum[wv - 1] : 0);  // exclusive prefix of this segment
#pragma unroll
    for (int i = 0; i < PER; i++) {
        int idx = base + i;
        int ro = excl + local[i];
        cur[idx] = ro + (int)poff[(size_t)p * NB + idx];
        if (p == 0 && idx <= NN) row_off[idx] = ro;
    }
    __syncthreads();
    int ebase = p * EPB;
    for (int i = t; i < EPB; i += 1024) {
        int d = dst[ebase + i];
        int slot = atomicAdd(&cur[d], 1);
        csr_src[slot] = src[ebase + i];
    }
}

// One wave per node; 128 bf16 dims = 64 uints of the full row.
// node = blockIdx.x ONLY -> beg/end/i live in SGPRs, csr_src index fetches go
// through the scalar pipe (s_load), gathers are saddr-form. Keep it that way:
// making node threadIdx-dependent forces the index stream onto VALU/TA (2x cost,
// measured rounds 8 and 15). Unroll 16 for MLP.
__global__ __launch_bounds__(64) void agg1_kernel(const uint* __restrict__ fb,
                                                  const int* __restrict__ row_off,
                                                  const int* __restrict__ csr_src,
                                                  const float* __restrict__ norm_dst,
                                                  uint* __restrict__ aggb) {
    int node = blockIdx.x;
    uint lane = threadIdx.x;
    int beg = row_off[node], end = row_off[node + 1];
    f32x2 acc = {0.f, 0.f};
    int i = beg;
    for (; i + 16 <= end; i += 16) {
        const uint* rp[16];
#pragma unroll
        for (int j = 0; j < 16; j++)
            rp[j] = fb + (uint)__builtin_amdgcn_readfirstlane(csr_src[i + j]) * 64u;
        uint a[16];
#pragma unroll
        for (int j = 0; j < 16; j++) a[j] = rp[j][lane];
#pragma unroll
        for (int j = 0; j < 16; j++) {
            f32x2 v; v.x = blo(a[j]); v.y = bhi(a[j]);
            acc += v;
        }
    }
    for (; i + 8 <= end; i += 8) {
        const uint* rp[8];
#pragma unroll
        for (int j = 0; j < 8; j++)
            rp[j] = fb + (uint)__builtin_amdgcn_readfirstlane(csr_src[i + j]) * 64u;
        uint a[8];
#pragma unroll
        for (int j = 0; j < 8; j++) a[j] = rp[j][lane];
#pragma unroll
        for (int j = 0; j < 8; j++) {
            f32x2 v; v.x = blo(a[j]); v.y = bhi(a[j]);
            acc += v;
        }
    }
    for (; i < end; i++) {
        const uint* rp = fb + (uint)__builtin_amdgcn_readfirstlane(csr_src[i]) * 64u;
        uint a = rp[lane];
        f32x2 v; v.x = blo(a); v.y = bhi(a);
        acc += v;
    }
    float nd = norm_dst[node];
    aggb[node * 64 + lane] = (uint)f2b(acc.x * nd) | ((uint)f2b(acc.y * nd) << 16);
}

// Sliced 512-dim gather with XCD-aware (node, slice) mapping.
// xcd = b&7 (round-robin dispatch), slice = xcd&3, node = (b>>3)*2 + (xcd>>2).
// Each XCD touches ONE 2.56 MB slice of hb -> per-XCD-L2 resident.
// node/slice from blockIdx ONLY (scalar index pipe — see agg1 note).
__global__ __launch_bounds__(64) void agg2_kernel(const uint* __restrict__ hb,
                                                  const int* __restrict__ row_off,
                                                  const int* __restrict__ csr_src,
                                                  const float* __restrict__ norm_dst,
                                                  uint* __restrict__ aggb) {
    uint b = blockIdx.x;
    uint xcd = b & 7u;
    int node = (int)((b >> 3) * 2u + (xcd >> 2));
    uint t = (xcd & 3u) * 64u + threadIdx.x;  // uint index 0..255
    int beg = row_off[node], end = row_off[node + 1];
    f32x2 acc = {0.f, 0.f};
    int i = beg;
    for (; i + 16 <= end; i += 16) {
        const uint* rp[16];
#pragma unroll
        for (int j = 0; j < 16; j++)
            rp[j] = hb + (uint)__builtin_amdgcn_readfirstlane(csr_src[i + j]) * 256u;
        uint a[16];
#pragma unroll
        for (int j = 0; j < 16; j++) a[j] = rp[j][t];
#pragma unroll
        for (int j = 0; j < 16; j++) {
            f32x2 v; v.x = blo(a[j]); v.y = bhi(a[j]);
            acc += v;
        }
    }
    for (; i + 8 <= end; i += 8) {
        const uint* rp[8];
#pragma unroll
        for (int j = 0; j < 8; j++)
            rp[j] = hb + (uint)__builtin_amdgcn_readfirstlane(csr_src[i + j]) * 256u;
        uint a[8];
#pragma unroll
        for (int j = 0; j < 8; j++) a[j] = rp[j][t];
#pragma unroll
        for (int j = 0; j < 8; j++) {
            f32x2 v; v.x = blo(a[j]); v.y = bhi(a[j]);
            acc += v;
        }
    }
    for (; i < end; i++) {
        const uint* rp = hb + (uint)__builtin_amdgcn_readfirstlane(csr_src[i]) * 256u;
        uint a = rp[t];
        f32x2 v; v.x = blo(a); v.y = bhi(a);
        acc += v;
    }
    float nd = norm_dst[node];
    aggb[(uint)node * 256u + t] = (uint)f2b(acc.x * nd) | ((uint)f2b(acc.y * nd) << 16);
}

// bf16 MFMA GEMM: C[M][N] = A[M][K] @ Bt[N][K]^T (+bias).
// BM=128, BN=64, BK=32, 256 threads = 4 waves (2x2 of 64x32), double-buffered
// LDS, 2-phase schedule: stage(next) -> ds_read/MFMA(cur) -> one barrier/K-step.
// BN=64 doubles the grid (632 blocks) -> tail 1.5 vs 2.0 tile-units on 256 CUs.
// Fragment-ordered LDS via global_load_lds with pre-swizzled per-lane source.
// A must be padded to BM-multiple rows (OOB rows read garbage, masked at C-write).
// EPI 0: fp32 out = acc + bias.   EPI 1: bf16 out = relu(acc+bias) * scale[row].
template <int EPI>
__global__ __launch_bounds__(256) void gemm_bf16_kernel(const ushort* __restrict__ A,
                                                        const ushort* __restrict__ Bt,
                                                        const float* __restrict__ bias,
                                                        const float* __restrict__ scale,
                                                        void* __restrict__ Cout,
                                                        int M, int K, int N) {
    __shared__ __align__(16) ushort As[2][128 * 32];  // 8 KB each, fragment order
    __shared__ __align__(16) ushort Bs[2][64 * 32];   // 4 KB each
    int tid = threadIdx.x;
    int lane = tid & 63;
    int wid = tid >> 6;
    int bm = blockIdx.x * 128;
    int bn = blockIdx.y * 64;
    int wm = (wid & 1) * 64;
    int wn = (wid >> 1) * 32;

    // Pre-swizzled source coords: LDS chunk c holds (row, kq):
    // row = ((c>>6)<<4)|(c&15), kq = (c>>4)&3.
    int c0 = tid, c1 = 256 + tid;
    int row0 = ((c0 >> 6) << 4) | (c0 & 15), kq0 = (c0 >> 4) & 3;
    int row1 = ((c1 >> 6) << 4) | (c1 & 15), kq1 = (c1 >> 4) & 3;
    const ushort* sA0 = A + (size_t)(bm + row0) * K + kq0 * 8;
    const ushort* sA1 = A + (size_t)(bm + row1) * K + kq1 * 8;
    const ushort* sB0 = Bt + (size_t)(bn + row0) * K + kq0 * 8;  // rows 0..63
    uint lo0 = (uint)(wid * 64) * 8u;          // ushort index of this wave's chunk group 0
    uint lo1 = (uint)(256 + wid * 64) * 8u;    // group 1 (A only)

    f32x4 acc[4][2] = {};

    const int NT = K / 32;
    // prologue: stage tile 0 into buffer 0
    gl_lds16(sA0, &As[0][lo0]);
    gl_lds16(sA1, &As[0][lo1]);
    gl_lds16(sB0, &Bs[0][lo0]);
    __syncthreads();

    int cur = 0;
    for (int t = 0; t < NT; t++) {
        if (t + 1 < NT) {  // stage next tile into the other buffer
            int kn = (t + 1) * 32;
            gl_lds16(sA0 + kn, &As[cur ^ 1][lo0]);
            gl_lds16(sA1 + kn, &As[cur ^ 1][lo1]);
            gl_lds16(sB0 + kn, &Bs[cur ^ 1][lo0]);
        }
        short8 af[4], bfr[2];
        int fo = ((lane >> 4) << 4) + (lane & 15);
#pragma unroll
        for (int i = 0; i < 4; i++) {
            int j = (((wm >> 4) + i) << 6) + fo;
            af[i] = *(const short8*)(&As[cur][j * 8]);
        }
#pragma unroll
        for (int i = 0; i < 2; i++) {
            int j = (((wn >> 4) + i) << 6) + fo;
            bfr[i] = *(const short8*)(&Bs[cur][j * 8]);
        }
#pragma unroll
        for (int i = 0; i < 4; i++)
#pragma unroll
            for (int jn = 0; jn < 2; jn++)
                acc[i][jn] = __builtin_amdgcn_mfma_f32_16x16x32_bf16(af[i], bfr[jn], acc[i][jn], 0, 0, 0);
        if (t + 1 < NT) {
            __syncthreads();  // drains next-tile vmcnt + guards buffer swap
            cur ^= 1;
        }
    }

#pragma unroll
    for (int i = 0; i < 4; i++) {
#pragma unroll
        for (int jn = 0; jn < 2; jn++) {
            int col = bn + wn + jn * 16 + (lane & 15);
            float bv = bias[col];
#pragma unroll
            for (int r = 0; r < 4; r++) {
                int gm = bm + wm + i * 16 + ((lane >> 4) << 2) + r;
                if (gm < M) {
                    float v = acc[i][jn][r] + bv;
                    if (EPI == 1) {
                        v = fmaxf(v, 0.f) * scale[gm];
                        ((ushort*)Cout)[(size_t)gm * N + col] = f2b(v);
                    } else {
                        ((float*)Cout)[(size_t)gm * N + col] = v;
                    }
                }
            }
        }
    }
}

extern "C" void kernel_launch(void* const* d_in, const int* in_sizes, int n_in,
                              void* d_out, int out_size, void* d_ws, size_t ws_size,
                              hipStream_t stream) {
    const float* feat = (const float*)d_in[0];
    const int* ei = (const int*)d_in[1];
    const float* W1 = (const float*)d_in[2];
    const float* b1 = (const float*)d_in[3];
    const float* W2 = (const float*)d_in[4];
    const float* b2 = (const float*)d_in[5];
    float* out = (float*)d_out;

    const int* src = ei;
    const int* dst = ei + NE;
    const int NNP = 10112;  // NN padded to BM=128 multiple (A-panel OOB safety)

    char* ws = (char*)d_ws;
    size_t off = 0;
    auto alloc = [&](size_t bytes) -> void* {
        void* p = ws + off;
        off += (bytes + 255) & ~(size_t)255;
        return p;
    };
    // ---- fixed region ----
    int* row_off = (int*)alloc((NN + 16) * sizeof(int));
    int* deg_in = (int*)alloc(NB * sizeof(int));
    float* norm_src = (float*)alloc(NN * sizeof(float));
    float* norm_dst = (float*)alloc(NN * sizeof(float));
    int* csr_src = (int*)alloc(NE * sizeof(int));
    ushort* featb = (ushort*)alloc((size_t)NN * IN_DIM * 2);
    ushort* W1t = (ushort*)alloc((size_t)HID_DIM * IN_DIM * 2);
    ushort* W2t = (ushort*)alloc((size_t)OUT_DIM * HID_DIM * 2);
    // ---- union region: prep {pcnt, poff} overlaps main {agg1b, hb, agg2b}.
    // Safe: pcnt last read in colreduce, poff last read in fillfeat; agg1b first
    // written by agg1, hb by gemm1, agg2b by agg2 — all strictly later.
    size_t union_base = off;
    uint* pcnt = (uint*)alloc((size_t)P_PART * NB * sizeof(uint));        // 5.24 MB packed
    ushort* poff = (ushort*)alloc((size_t)P_PART * NB * sizeof(ushort));  // 2.62 MB
    off = union_base;
    ushort* agg1b = (ushort*)alloc((size_t)NNP * IN_DIM * 2);   // padded A-panel
    ushort* hb = (ushort*)alloc((size_t)NN * HID_DIM * 2);      // 10.24 MB
    ushort* agg2b = (ushort*)alloc((size_t)NNP * HID_DIM * 2);  // padded A-panel

    // ---- graph prep (no global atomics) + W transposes ----
    histw_kernel<<<448, 1024, 0, stream>>>(ei, pcnt, W1, W1t, W2, W2t);
    colreduce_kernel<<<NB / 256, 256, 0, stream>>>(pcnt, poff, deg_in, norm_src, norm_dst);
    fillfeat_kernel<<<128 + 313, 1024, 0, stream>>>(src, dst, deg_in, poff, row_off, csr_src,
                                                    feat, norm_src, featb);

    // ---- layer 1 ----
    agg1_kernel<<<NN, 64, 0, stream>>>((const uint*)featb, row_off, csr_src, norm_dst, (uint*)agg1b);
    {
        dim3 grid(NNP / 128, HID_DIM / 64);
        gemm_bf16_kernel<1><<<grid, 256, 0, stream>>>(agg1b, W1t, b1, norm_src, hb, NN, IN_DIM, HID_DIM);
    }
    // ---- layer 2 (XCD-aware sliced gather: 40000 1-D blocks) ----
    agg2_kernel<<<NN / 2 * 8, 64, 0, stream>>>((const uint*)hb, row_off, csr_src, norm_dst, (uint*)agg2b);
    {
        dim3 grid(NNP / 128, OUT_DIM / 64);
        gemm_bf16_kernel<0><<<grid, 256, 0, stream>>>(agg2b, W2t, b2, nullptr, out, NN, HID_DIM, OUT_DIM);
    }
}